// Round 9
// baseline (1049.368 us; speedup 1.0000x reference)
//
#include <hip/hip_runtime.h>
#include <math.h>

// ---------------------------------------------------------------------------
// (B, Cin, Cout, Rout, N1, N2) = (8, 256, 512, 256, 4096, 1024)
// Activations token-major X[b][n][c] (c contiguous) except v [c][m].
// LN/softmax fused into GEMM epilogues (stats) / staging (apply).
// R9: all 8 GEMMs in ONE persistent 512-block kernel with in-kernel grid
// barriers (monotonic counter + agent-scope fences) -> 16 -> 7 dispatches.
// ---------------------------------------------------------------------------

typedef __attribute__((ext_vector_type(8))) short short8x;
typedef __attribute__((ext_vector_type(4))) float f32x4;

__device__ __forceinline__ unsigned short f2b(float f) {
  unsigned int u = __float_as_uint(f);
  unsigned int r = u + 0x7FFFu + ((u >> 16) & 1u);
  return (unsigned short)(r >> 16);
}
__device__ __forceinline__ float b2f(unsigned short h) {
  return __uint_as_float(((unsigned int)h) << 16);
}

__device__ __forceinline__ void cp16(const unsigned short* g, unsigned short* l) {
  __builtin_amdgcn_global_load_lds(
      (const __attribute__((address_space(1))) void*)g,
      (__attribute__((address_space(3))) void*)l, 16, 0, 0);
}

// grid barrier: monotonic counter; release(fence)+arrive, spin(acquire), fence.
__device__ __forceinline__ void gbar(int* bar, int target) {
  __syncthreads();
  __threadfence();
  if (threadIdx.x == 0) {
    __hip_atomic_fetch_add(bar, 1, __ATOMIC_ACQ_REL, __HIP_MEMORY_SCOPE_AGENT);
    while (__hip_atomic_load(bar, __ATOMIC_ACQUIRE, __HIP_MEMORY_SCOPE_AGENT) < target)
      __builtin_amdgcn_s_sleep(2);
  }
  __syncthreads();
  __threadfence();
}

// ===========================================================================
// prep: y=0..6 weight f32->bf16; y=7 transpose l2 + pos_q (+l2T copy);
//       y=8 selA: q1v[b][o] = sum_c q1w[o,c]*l1[b,c,0]
// ===========================================================================
__global__ void __launch_bounds__(256) prep_kernel(
    const float* w0, const float* w1, const float* w2, const float* w3,
    const float* w4, const float* w5, const float* w6,
    unsigned short* d0, unsigned short* d1, unsigned short* d2,
    unsigned short* d3, unsigned short* d4, unsigned short* d5,
    unsigned short* d6,
    const float* __restrict__ l1, const float* __restrict__ q1w,
    float* __restrict__ q1v,
    const float* __restrict__ l2, const float* __restrict__ xyz2,
    const float* __restrict__ posw, unsigned short* __restrict__ qinT,
    float* __restrict__ l2T) {
  __shared__ float tile[64][65];
  __shared__ float sx[3][64];
  __shared__ float col[256];
  const int t = threadIdx.x;
  const int y = blockIdx.y;

  if (y == 7) {  // transpose + pos_q
    if (blockIdx.x >= 1024) return;
    const int b = blockIdx.x >> 7;
    const int rem = blockIdx.x & 127;
    const int n0 = (rem & 15) * 64, c0 = (rem >> 4) * 64;
    const int tx = t & 63, ty = t >> 6;
    const float* l2b = l2 + (long)b * 512 * 1024;
    for (int r = 0; r < 16; ++r) {
      const int c = ty * 16 + r;
      tile[c][tx] = l2b[(long)(c0 + c) * 1024 + n0 + tx];
    }
    if (ty < 3) sx[ty][tx] = xyz2[((long)b * 3 + ty) * 1024 + n0 + tx];
    __syncthreads();
    const int c = c0 + tx;
    const float p0 = posw[c * 3], p1 = posw[c * 3 + 1], p2 = posw[c * 3 + 2];
    for (int r = 0; r < 16; ++r) {
      const int nl = ty * 16 + r;
      const float val = tile[tx][nl];
      const long o = ((long)b * 1024 + n0 + nl) * 512 + c;
      l2T[o] = val;
      qinT[o] = f2b(val + p0 * sx[0][nl] + p1 * sx[1][nl] + p2 * sx[2][nl]);
    }
    return;
  }
  if (y == 8) {  // selA
    if (blockIdx.x >= 64) return;
    const int b = blockIdx.x >> 3;
    const int chunk = blockIdx.x & 7;
    col[t] = l1[(long)b * 256 * 4096 + (long)t * 4096];
    __syncthreads();
    const int lane = t & 63, wid = t >> 6;
    const float4 cv = *(const float4*)&col[lane * 4];
    const int obase = chunk * 64 + wid * 16;
#pragma unroll
    for (int oo = 0; oo < 16; ++oo) {
      const int o = obase + oo;
      const float4 wv = ((const float4*)(q1w + (long)o * 256))[lane];
      float s = wv.x * cv.x + wv.y * cv.y + wv.z * cv.z + wv.w * cv.w;
      s += __shfl_xor(s, 1); s += __shfl_xor(s, 2); s += __shfl_xor(s, 4);
      s += __shfl_xor(s, 8); s += __shfl_xor(s, 16); s += __shfl_xor(s, 32);
      if (lane == 0) q1v[b * 512 + o] = s;
    }
    return;
  }
  // weight conversion
  const float* src;
  unsigned short* dst;
  int n;
  switch (y) {
    case 0: src = w0; dst = d0; n = 65536; break;
    case 1: src = w1; dst = d1; n = 131072; break;
    case 2: src = w2; dst = d2; n = 262144; break;
    case 3: src = w3; dst = d3; n = 262144; break;
    case 4: src = w4; dst = d4; n = 262144; break;
    case 5: src = w5; dst = d5; n = 262144; break;
    default: src = w6; dst = d6; n = 131072; break;
  }
  const int i = (blockIdx.x * 256 + t) * 4;
  if (i < n) {
    const float4 v = *(const float4*)(src + i);
    ushort4 o;
    o.x = f2b(v.x); o.y = f2b(v.y); o.z = f2b(v.z); o.w = f2b(v.w);
    *(ushort4*)(dst + i) = o;
  }
}

// ===========================================================================
// selB: wvec[b][c] += sum_{o in chunk} k1w[o][c] * q1v[b][o]   (wvec zeroed)
// ===========================================================================
__global__ void __launch_bounds__(256) selB_kernel(
    const float* __restrict__ k1w, const float* __restrict__ q1v,
    float* __restrict__ wvec) {
  const int b = blockIdx.x;
  const int chunk = blockIdx.y;
  __shared__ float qs[64];
  const int t = threadIdx.x;
  if (t < 64) qs[t] = q1v[b * 512 + chunk * 64 + t];
  __syncthreads();
  float s = 0.f;
  const float* kp = k1w + (long)(chunk * 64) * 256 + t;
#pragma unroll 8
  for (int oo = 0; oo < 64; ++oo) s += kp[(long)oo * 256] * qs[oo];
  atomicAdd(&wvec[b * 256 + t], s);
}

// ===========================================================================
// scores[b,m] = sum_c wvec[b,c] * l1[b,c,m]   (f32 exact)
// ===========================================================================
__global__ void __launch_bounds__(256) sel_scores_kernel(
    const float* __restrict__ l1, const float* __restrict__ wvec,
    float* __restrict__ scores) {
  const int b = blockIdx.y;
  const int m = blockIdx.x * 256 + threadIdx.x;
  __shared__ float w[256];
  w[threadIdx.x] = wvec[b * 256 + threadIdx.x];
  __syncthreads();
  const float* base = l1 + (long)b * 256 * 4096 + m;
  float s = 0.f;
  for (int c = 0; c < 256; ++c) s += w[c] * base[(long)c * 4096];
  scores[b * 4096 + m] = s;
}

// ===========================================================================
// Exact top-1024 SET per batch (radix select), output index-sorted ascending.
// ===========================================================================
__global__ void __launch_bounds__(256) topk_select_kernel(
    const float* __restrict__ scores, int* __restrict__ idx_out) {
  const int b = blockIdx.x;
  const int t = threadIdx.x;
  __shared__ unsigned int keys[4096];
  __shared__ unsigned int hist[256];
  __shared__ unsigned int sc_prefix, sc_krem;
  __shared__ int s_bin;
  __shared__ unsigned int partial_gt[256], partial_eq[256];

  for (int m = t; m < 4096; m += 256) {
    unsigned int u = __float_as_uint(scores[b * 4096 + m]);
    u ^= (u & 0x80000000u) ? 0xFFFFFFFFu : 0x80000000u;
    keys[m] = u;
  }
  if (t == 0) { sc_prefix = 0u; sc_krem = 1024u; }
  __syncthreads();

  unsigned int prefmask = 0u;
  for (int shift = 24; shift >= 0; shift -= 8) {
    hist[t] = 0u;
    if (t == 0) s_bin = 0;
    __syncthreads();
    const unsigned int prefix = sc_prefix;
    for (int m = t; m < 4096; m += 256) {
      unsigned int key = keys[m];
      if ((key & prefmask) == prefix) atomicAdd(&hist[(key >> shift) & 255u], 1u);
    }
    __syncthreads();
    for (int off = 1; off < 256; off <<= 1) {
      unsigned int v = hist[t] + ((t + off < 256) ? hist[t + off] : 0u);
      __syncthreads();
      hist[t] = v;
      __syncthreads();
    }
    const unsigned int krem = sc_krem;
    if (hist[t] >= krem) atomicMax(&s_bin, t);
    __syncthreads();
    if (t == 0) {
      const int bin = s_bin;
      sc_krem = krem - ((bin < 255) ? hist[bin + 1] : 0u);
      sc_prefix = prefix | ((unsigned int)bin << shift);
    }
    prefmask |= (0xFFu << shift);
    __syncthreads();
  }
  const unsigned int cutoff = sc_prefix;
  const unsigned int need = sc_krem;

  unsigned int gt = 0u, eq = 0u;
  const int base = t * 16;
  for (int i = 0; i < 16; ++i) {
    unsigned int key = keys[base + i];
    gt += (key > cutoff);
    eq += (key == cutoff);
  }
  partial_gt[t] = gt;
  partial_eq[t] = eq;
  __syncthreads();
  for (int off = 1; off < 256; off <<= 1) {
    unsigned int g = partial_gt[t] + ((t >= off) ? partial_gt[t - off] : 0u);
    unsigned int e2 = partial_eq[t] + ((t >= off) ? partial_eq[t - off] : 0u);
    __syncthreads();
    partial_gt[t] = g;
    partial_eq[t] = e2;
    __syncthreads();
  }
  const unsigned int pref_gt = partial_gt[t] - gt;
  const unsigned int pref_eq = partial_eq[t] - eq;
  unsigned int pos = pref_gt + ((pref_eq < need) ? pref_eq : need);
  unsigned int eqr = pref_eq;
  for (int i = 0; i < 16; ++i) {
    unsigned int key = keys[base + i];
    bool sel = (key > cutoff);
    if (key == cutoff) sel = sel || (eqr++ < need);
    if (sel) idx_out[b * 1024 + (pos++)] = base + i;
  }
}

// ===========================================================================
// Gather (idx ascending): l1selT[b][j][c] bf16 token-major, p1selT f32.
// ===========================================================================
__global__ void __launch_bounds__(256) gather_sel_kernel(
    const float* __restrict__ l1, const float* __restrict__ xyz1,
    const int* __restrict__ idx, unsigned short* __restrict__ l1selT,
    float* __restrict__ p1selT) {
  const int b = blockIdx.z;
  const int j = blockIdx.x * 64 + (threadIdx.x & 63);
  const int cz = blockIdx.y;
  const int cg = threadIdx.x >> 6;
  const int ix = idx[b * 1024 + j];
  const float* src = l1 + (long)b * 256 * 4096 + ix;
  unsigned short* dst = l1selT + ((long)b * 1024 + j) * 256;
#pragma unroll
  for (int it = 0; it < 8; ++it) {
    const int c = cz * 128 + it * 16 + cg * 4;
    const float x0 = src[(long)(c + 0) * 4096];
    const float x1 = src[(long)(c + 1) * 4096];
    const float x2 = src[(long)(c + 2) * 4096];
    const float x3 = src[(long)(c + 3) * 4096];
    ushort4 o;
    o.x = f2b(x0); o.y = f2b(x1); o.z = f2b(x2); o.w = f2b(x3);
    *(ushort4*)&dst[c] = o;
  }
  if (cz == 0 && cg == 0) {
    float* dp = p1selT + ((long)b * 1024 + j) * 3;
#pragma unroll
    for (int d = 0; d < 3; ++d) dp[d] = xyz1[((long)b * 3 + d) * 4096 + ix];
  }
}

// ===========================================================================
// GEMM tile params + device tile function (BN=64, M-tile 128, BK=32 dbuf).
// ===========================================================================
struct GP {
  const unsigned short* A; long sA; int ldA;
  const unsigned short* Bt; long sB; int ldB; long sB8;
  void* Yv; long sY; int ldY;
  const float* bias; const float* res; long sR;
  int K; float alpha;
  const float* ts1; const float* ts2;
  const float* tg; const float* tb; float tslope;
  float* os1; float* os2;
  const float* kpos; const float* kpw; unsigned short* Y2;
};

template <int TRA, int TRB, bool BCOL, bool BROW, bool RES, int EPI>
__device__ void gemm_tile(const GP& p, int bx, int by, int bz,
                          unsigned short* ldsA, unsigned short* ldsB) {
  constexpr int BN = 64, JN = 2;
  constexpr int ASTR = 128 * 32, BSTR = BN * 32;
  const int tid = threadIdx.x;
  const int lane = tid & 63;
  const int wv = tid >> 6;
  const int wm = wv >> 1, wn = wv & 1;
  const int n0 = bx * BN, m0 = by * 128, b = bz;
  const unsigned short* A = p.A + (long)b * p.sA;
  const unsigned short* Bt = p.Bt + (long)(b & 7) * p.sB + (long)(b >> 3) * p.sB8;
  const int ldA = p.ldA, ldB = p.ldB, K = p.K;
  const int lane15 = lane & 15, q = lane >> 4;

  // A staging: 4 waves x 2 cp16 (32 rows each)
  const int srow0 = wv * 32 + (lane >> 2);
  const int srow1 = srow0 + 16;
  const int ks0 = ((lane & 3) ^ ((srow0 >> 1) & 3)) << 3;
  const int ks1 = ((lane & 3) ^ ((srow1 >> 1) & 3)) << 3;
  const unsigned short* gA0 = A + (long)(m0 + srow0) * ldA + ks0;
  const unsigned short* gA1 = A + (long)(m0 + srow1) * ldA + ks1;
  unsigned short* lA0[2] = {ldsA + (wv * 32) * 32, ldsA + ASTR + (wv * 32) * 32};
  unsigned short* lA1[2] = {ldsA + (wv * 32 + 16) * 32, ldsA + ASTR + (wv * 32 + 16) * 32};
  // B staging: 4 waves x 1 cp16 (16 rows each)
  const int srowB = wv * 16 + (lane >> 2);
  const int ksB = ((lane & 3) ^ ((srowB >> 1) & 3)) << 3;
  const unsigned short* gB0 = Bt + (long)(n0 + srowB) * ldB + ksB;
  unsigned short* lB0[2] = {ldsB + (wv * 16) * 32, ldsB + BSTR + (wv * 16) * 32};

  // transform staging (LN while writing LDS)
  constexpr bool TR = (TRA + TRB) != 0;
  constexpr int TROWS = TRA ? 128 : BN;
  constexpr int TSH = (TROWS == 128) ? 7 : 6;
  constexpr int TCH = (TROWS == 128) ? 2 : 1;
  const int trow = tid & (TROWS - 1), tpart = tid >> TSH;
  float t_mu = 0.f, t_rs = 0.f;
  const unsigned short* tsrc = nullptr;
  int toff[2] = {0, 0};
  int tkof = 0;
  if constexpr (TR) {
    const int row0 = (TRA ? m0 : n0) + trow;
    const int ridx = (b & 7) * 1024 + row0;
    const float Cf = (float)K;
    const float s1v = p.ts1[ridx], s2v = p.ts2[ridx];
    t_mu = s1v / Cf;
    t_rs = rsqrtf(s2v / Cf - t_mu * t_mu + 1e-5f);
    tkof = tpart * (TCH * 8);
    tsrc = (TRA ? A + (long)row0 * ldA : Bt + (long)row0 * ldB) + tkof;
    const int sw = (trow >> 1) & 3;
#pragma unroll
    for (int c = 0; c < TCH; ++c)
      toff[c] = trow * 32 + (((tpart * TCH + c) ^ sw) << 3);
  }

  auto t_apply = [&](int kk, short8x r0, short8x r1, int buf) {
    unsigned short* base = TRA ? (ldsA + buf * ASTR) : (ldsB + buf * BSTR);
    const short8x rr[2] = {r0, r1};
#pragma unroll
    for (int c = 0; c < TCH; ++c) {
      union { short8x v; unsigned short u[8]; } a0, w0;
      a0.v = rr[c];
      const float4* gp = (const float4*)(p.tg + kk + tkof + c * 8);
      const float4* bp = (const float4*)(p.tb + kk + tkof + c * 8);
      const float4 g0 = gp[0], g1 = gp[1];
      const float4 e0 = bp[0], e1 = bp[1];
      const float gg[8] = {g0.x, g0.y, g0.z, g0.w, g1.x, g1.y, g1.z, g1.w};
      const float ee[8] = {e0.x, e0.y, e0.z, e0.w, e1.x, e1.y, e1.z, e1.w};
#pragma unroll
      for (int u = 0; u < 8; ++u) {
        float y = (b2f(a0.u[u]) - t_mu) * t_rs * gg[u] + ee[u];
        y = y > 0.f ? y : p.tslope * y;
        w0.u[u] = f2b(y);
      }
      *(short8x*)&base[toff[c]] = w0.v;
    }
  };

  short8x tr0 = {}, tr1 = {};
  if constexpr (TR) {
    tr0 = *(const short8x*)(tsrc + 0);
    if constexpr (TCH == 2) tr1 = *(const short8x*)(tsrc + 8);
  }
  if constexpr (!TRA) { cp16(gA0, lA0[0]); cp16(gA1, lA1[0]); }
  if constexpr (!TRB) { cp16(gB0, lB0[0]); }
  if constexpr (TR) t_apply(0, tr0, tr1, 0);

  f32x4 acc[4][JN] = {};
  int cur = 0;
  for (int k0 = 0; k0 < K; k0 += 32) {
    __syncthreads();
    const bool nxt = (k0 + 32 < K);
    if (nxt) {
      const int nk = k0 + 32;
      if constexpr (!TRA) { cp16(gA0 + nk, lA0[cur ^ 1]); cp16(gA1 + nk, lA1[cur ^ 1]); }
      if constexpr (!TRB) { cp16(gB0 + nk, lB0[cur ^ 1]); }
      if constexpr (TR) {
        tr0 = *(const short8x*)(tsrc + nk);
        if constexpr (TCH == 2) tr1 = *(const short8x*)(tsrc + nk + 8);
      }
    }
    short8x af[4], bfr[JN];
#pragma unroll
    for (int i = 0; i < 4; ++i) {
      const int m = wm * 64 + i * 16 + lane15;
      af[i] = *(const short8x*)&ldsA[cur * ASTR + m * 32 + ((q ^ ((m >> 1) & 3)) << 3)];
    }
#pragma unroll
    for (int j = 0; j < JN; ++j) {
      const int n = wn * (BN / 2) + j * 16 + lane15;
      bfr[j] = *(const short8x*)&ldsB[cur * BSTR + n * 32 + ((q ^ ((n >> 1) & 3)) << 3)];
    }
#pragma unroll
    for (int i = 0; i < 4; ++i)
#pragma unroll
      for (int j = 0; j < JN; ++j)
        acc[i][j] = __builtin_amdgcn_mfma_f32_16x16x32_bf16(af[i], bfr[j], acc[i][j], 0, 0, 0);
    if (nxt) {
      if constexpr (TR) t_apply(k0 + 32, tr0, tr1, cur ^ 1);
    }
    cur ^= 1;
  }

  // epilogue (C/D layout: col=lane&15, row=(lane>>4)*4+reg)
  float* Yf = (float*)p.Yv;
  unsigned short* Yh = (unsigned short*)p.Yv;
  if constexpr (EPI == 0) Yf += (long)b * p.sY; else Yh += (long)b * p.sY;
  unsigned short* Y2 = p.Y2;
  if constexpr (EPI == 5) Y2 += (long)b * p.sY;
  const float* res = p.res;
  if constexpr (RES) res += (long)b * p.sR;
  const int ldY = p.ldY;
  float inv_[4];
  float kq0[4], kq1[4], kq2[4];
  float ssum[4][4], ssq[4][4];
#pragma unroll
  for (int i = 0; i < 4; ++i)
#pragma unroll
    for (int r = 0; r < 4; ++r) { ssum[i][r] = 0.f; ssq[i][r] = 0.f; }

#pragma unroll
  for (int i = 0; i < 4; ++i) {
    if constexpr (EPI == 4) {
#pragma unroll
      for (int r = 0; r < 4; ++r)
        inv_[r] = 1.f / p.ts1[(b & 7) * 1024 + m0 + wm * 64 + i * 16 + q * 4 + r];
    }
    if constexpr (EPI == 5) {
#pragma unroll
      for (int r = 0; r < 4; ++r) {
        const int m_g = m0 + wm * 64 + i * 16 + q * 4 + r;
        const float* pp = p.kpos + ((long)b * 1024 + m_g) * 3;
        kq0[r] = pp[0]; kq1[r] = pp[1]; kq2[r] = pp[2];
      }
    }
#pragma unroll
    for (int j = 0; j < JN; ++j) {
      const int n_g = n0 + wn * (BN / 2) + j * 16 + lane15;
      const float bc = BCOL ? p.bias[n_g] : 0.f;
      float pw0 = 0.f, pw1 = 0.f, pw2 = 0.f;
      if constexpr (EPI == 5) {
        pw0 = p.kpw[n_g * 3]; pw1 = p.kpw[n_g * 3 + 1]; pw2 = p.kpw[n_g * 3 + 2];
      }
#pragma unroll
      for (int r = 0; r < 4; ++r) {
        const int m_g = m0 + wm * 64 + i * 16 + q * 4 + r;
        float y = acc[i][j][r] * p.alpha;
        if constexpr (EPI == 4) y *= inv_[r];
        if constexpr (BCOL) y += bc;
        if constexpr (BROW) y += p.bias[m_g];
        if constexpr (RES) y += res[(long)m_g * ldY + n_g];
        if constexpr (EPI == 3) y = __expf(y);
        const long off = (long)m_g * ldY + n_g;
        if constexpr (EPI == 0) Yf[off] = y;
        else Yh[off] = f2b(y);
        if constexpr (EPI == 5)
          Y2[off] = f2b(y + pw0 * kq0[r] + pw1 * kq1[r] + pw2 * kq2[r]);
        if constexpr (EPI == 2 || EPI == 3 || EPI == 4) {
          ssum[i][r] += y; ssq[i][r] += y * y;
        }
      }
    }
  }
  if constexpr (EPI == 2 || EPI == 4) {
#pragma unroll
    for (int i = 0; i < 4; ++i)
#pragma unroll
      for (int r = 0; r < 4; ++r) {
        float s = ssum[i][r], q2 = ssq[i][r];
        s += __shfl_xor(s, 1); q2 += __shfl_xor(q2, 1);
        s += __shfl_xor(s, 2); q2 += __shfl_xor(q2, 2);
        s += __shfl_xor(s, 4); q2 += __shfl_xor(q2, 4);
        s += __shfl_xor(s, 8); q2 += __shfl_xor(q2, 8);
        if (lane15 == 0) {
          const int ridx = (b & 7) * 1024 + m0 + wm * 64 + i * 16 + q * 4 + r;
          atomicAdd(&p.os1[ridx], s);
          atomicAdd(&p.os2[ridx], q2);
        }
      }
  } else if constexpr (EPI == 3) {
#pragma unroll
    for (int i = 0; i < 4; ++i)
#pragma unroll
      for (int r = 0; r < 4; ++r) {
        float s = ssum[i][r];
        s += __shfl_xor(s, 1);
        s += __shfl_xor(s, 2);
        s += __shfl_xor(s, 4);
        s += __shfl_xor(s, 8);
        if (lane15 == 0) {
          const int ridx = (b & 7) * 1024 + m0 + wm * 64 + i * 16 + q * 4 + r;
          atomicAdd(&p.os1[ridx], s);
        }
      }
  }
}

// ===========================================================================
// Mega kernel: 7 GEMM phases with in-kernel grid barriers. 512 blocks.
// ===========================================================================
__global__ void __launch_bounds__(256, 2) mega_kernel(
    char* ws, float* outp,
    const float* mlp_b1, const float* mlp_g1, const float* mlp_be1,
    const float* mlp_b2, const float* posw,
    const float* norm_g, const float* norm_b,
    const float* m1_b1, const float* m1_g, const float* m1_be,
    const float* m1_b2) {
  __shared__ __align__(16) unsigned short sA[2 * 128 * 32];
  __shared__ __align__(16) unsigned short sB[2 * 64 * 32];
  const long MiB = 1048576;
  unsigned short* wb_mlp_w1 = (unsigned short*)(ws + 0);
  unsigned short* wb_mlp_w2 = (unsigned short*)(ws + 131072);
  unsigned short* wb_qw = (unsigned short*)(ws + 393216);
  unsigned short* wb_vw = (unsigned short*)(ws + 1441792);
  unsigned short* wb_m1w1 = (unsigned short*)(ws + 1966080);
  unsigned short* wb_m1w2 = (unsigned short*)(ws + 2490368);
  float* p1selT = (float*)(ws + 2924544);
  float* rowsum = (float*)(ws + 3407872);
  float* h1_s1 = (float*)(ws + 3440640);
  float* h1_s2 = (float*)(ws + 3473408);
  float* o_s1 = (float*)(ws + 3506176);
  float* o_s2 = (float*)(ws + 3538944);
  float* g1_s1 = (float*)(ws + 3571712);
  float* g1_s2 = (float*)(ws + 3604480);
  int* bar = (int*)(ws + 3637248);
  unsigned short* l1selT = (unsigned short*)(ws + 4 * MiB);
  unsigned short* h1 = (unsigned short*)(ws + 8 * MiB);
  unsigned short* x2T = (unsigned short*)(ws + 12 * MiB);
  unsigned short* qinT = (unsigned short*)(ws + 20 * MiB);
  unsigned short* kinT = (unsigned short*)(ws + 28 * MiB);
  float* l2T = (float*)(ws + 36 * MiB);
  unsigned short* qT = (unsigned short*)(ws + 52 * MiB);
  unsigned short* kT = (unsigned short*)(ws + 60 * MiB);
  unsigned short* vbf = (unsigned short*)(ws + 68 * MiB);
  unsigned short* pbuf = (unsigned short*)(ws + 76 * MiB);
  unsigned short* obuf = (unsigned short*)(ws + 92 * MiB);
  unsigned short* g1buf = (unsigned short*)(ws + 100 * MiB);

  const long T256 = 1024L * 256, T512 = 1024L * 512, T1024 = 1024L * 1024;
  const float inv_scale = 0.04419417382415922f;  // 1/sqrt(512)
  const int NB = gridDim.x;

  // P1: G1  h1 = l1selT·mlp_w1^T + b1 -> bf16 + LN stats   (4,8,8)=256
  {
    GP p{.A = l1selT, .sA = T256, .ldA = 256, .Bt = wb_mlp_w1, .sB = 0,
         .ldB = 256, .sB8 = 0, .Yv = h1, .sY = T256, .ldY = 256,
         .bias = mlp_b1, .res = nullptr, .sR = 0, .K = 256, .alpha = 1.0f,
         .ts1 = nullptr, .ts2 = nullptr, .tg = nullptr, .tb = nullptr,
         .tslope = 0.f, .os1 = h1_s1, .os2 = h1_s2, .kpos = nullptr,
         .kpw = nullptr, .Y2 = nullptr};
    for (int t = blockIdx.x; t < 256; t += NB)
      gemm_tile<0, 0, true, false, false, 2>(p, t & 3, (t >> 2) & 7, t >> 5, sA, sB);
  }
  gbar(bar, NB * 1);

  // P2: G2  x2T = relu(LN(h1))·mlp_w2^T + b2 (+kinT)       (8,8,8)=512
  {
    GP p{.A = h1, .sA = T256, .ldA = 256, .Bt = wb_mlp_w2, .sB = 0,
         .ldB = 256, .sB8 = 0, .Yv = x2T, .sY = T512, .ldY = 512,
         .bias = mlp_b2, .res = nullptr, .sR = 0, .K = 256, .alpha = 1.0f,
         .ts1 = h1_s1, .ts2 = h1_s2, .tg = mlp_g1, .tb = mlp_be1,
         .tslope = 0.f, .os1 = nullptr, .os2 = nullptr, .kpos = p1selT,
         .kpw = posw, .Y2 = kinT};
    for (int t = blockIdx.x; t < 512; t += NB)
      gemm_tile<1, 0, true, false, false, 5>(p, t & 7, (t >> 3) & 7, t >> 6, sA, sB);
  }
  gbar(bar, NB * 2);

  // P3: Gqk (8,8,16)=1024  +  Gv (16,4,8)=512  -> 1536 tiles, one phase
  {
    GP pq{.A = qinT, .sA = T512, .ldA = 512, .Bt = wb_qw, .sB = 0,
          .ldB = 512, .sB8 = 262144, .Yv = qT, .sY = T512, .ldY = 512,
          .bias = nullptr, .res = nullptr, .sR = 0, .K = 512, .alpha = 1.0f,
          .ts1 = nullptr, .ts2 = nullptr, .tg = nullptr, .tb = nullptr,
          .tslope = 0.f, .os1 = nullptr, .os2 = nullptr, .kpos = nullptr,
          .kpw = nullptr, .Y2 = nullptr};
    GP pv{.A = wb_vw, .sA = 0, .ldA = 512, .Bt = x2T, .sB = T512,
          .ldB = 512, .sB8 = 0, .Yv = vbf, .sY = T512, .ldY = 1024,
          .bias = nullptr, .res = nullptr, .sR = 0, .K = 512, .alpha = 1.0f,
          .ts1 = nullptr, .ts2 = nullptr, .tg = nullptr, .tb = nullptr,
          .tslope = 0.f, .os1 = nullptr, .os2 = nullptr, .kpos = nullptr,
          .kpw = nullptr, .Y2 = nullptr};
    for (int t = blockIdx.x; t < 1536; t += NB) {
      if (t < 1024) {
        gemm_tile<0, 0, false, false, false, 1>(pq, t & 7, (t >> 3) & 7, t >> 6, sA, sB);
      } else {
        const int u = t - 1024;
        gemm_tile<0, 0, false, false, false, 1>(pv, u & 15, (u >> 4) & 3, u >> 6, sA, sB);
      }
    }
  }
  gbar(bar, NB * 3);

  // P4: G7  p = exp(qT·kT^T/scale) -> bf16 + rowsum        (16,8,8)=1024
  {
    GP p{.A = qT, .sA = T512, .ldA = 512, .Bt = kT, .sB = T512,
         .ldB = 512, .sB8 = 0, .Yv = pbuf, .sY = T1024, .ldY = 1024,
         .bias = nullptr, .res = nullptr, .sR = 0, .K = 512,
         .alpha = inv_scale, .ts1 = nullptr, .ts2 = nullptr, .tg = nullptr,
         .tb = nullptr, .tslope = 0.f, .os1 = rowsum, .os2 = nullptr,
         .kpos = nullptr, .kpw = nullptr, .Y2 = nullptr};
    for (int t = blockIdx.x; t < 1024; t += NB)
      gemm_tile<0, 0, false, false, false, 3>(p, t & 15, (t >> 4) & 7, t >> 7, sA, sB);
  }
  gbar(bar, NB * 4);

  // P5: G8  o = (p·v^T)/rowsum + l2T -> bf16 + LN stats    (8,8,8)=512
  {
    GP p{.A = pbuf, .sA = T1024, .ldA = 1024, .Bt = vbf, .sB = T512,
         .ldB = 1024, .sB8 = 0, .Yv = obuf, .sY = T512, .ldY = 512,
         .bias = nullptr, .res = l2T, .sR = T512, .K = 1024, .alpha = 1.0f,
         .ts1 = rowsum, .ts2 = nullptr, .tg = nullptr, .tb = nullptr,
         .tslope = 0.f, .os1 = o_s1, .os2 = o_s2, .kpos = nullptr,
         .kpw = nullptr, .Y2 = nullptr};
    for (int t = blockIdx.x; t < 512; t += NB)
      gemm_tile<0, 0, false, false, true, 4>(p, t & 7, (t >> 3) & 7, t >> 6, sA, sB);
  }
  gbar(bar, NB * 5);

  // P6: G9  g1 = leaky(LN(o))·m1_w1^T + b1 -> bf16 + stats (8,8,8)=512
  {
    GP p{.A = obuf, .sA = T512, .ldA = 512, .Bt = wb_m1w1, .sB = 0,
         .ldB = 512, .sB8 = 0, .Yv = g1buf, .sY = T512, .ldY = 512,
         .bias = m1_b1, .res = nullptr, .sR = 0, .K = 512, .alpha = 1.0f,
         .ts1 = o_s1, .ts2 = o_s2, .tg = norm_g, .tb = norm_b,
         .tslope = 0.01f, .os1 = g1_s1, .os2 = g1_s2, .kpos = nullptr,
         .kpw = nullptr, .Y2 = nullptr};
    for (int t = blockIdx.x; t < 512; t += NB)
      gemm_tile<1, 0, true, false, false, 2>(p, t & 7, (t >> 3) & 7, t >> 6, sA, sB);
  }
  gbar(bar, NB * 6);

  // P7: G10 out = m1_w2·relu(LN(g1))^T + b2 -> f32 d_out   (16,2,8)=256
  {
    GP p{.A = wb_m1w2, .sA = 0, .ldA = 512, .Bt = g1buf, .sB = T512,
         .ldB = 512, .sB8 = 0, .Yv = outp, .sY = 256L * 1024, .ldY = 1024,
         .bias = m1_b2, .res = nullptr, .sR = 0, .K = 512, .alpha = 1.0f,
         .ts1 = g1_s1, .ts2 = g1_s2, .tg = m1_g, .tb = m1_be,
         .tslope = 0.f, .os1 = nullptr, .os2 = nullptr, .kpos = nullptr,
         .kpw = nullptr, .Y2 = nullptr};
    for (int t = blockIdx.x; t < 256; t += NB)
      gemm_tile<0, 1, false, true, false, 0>(p, t & 15, (t >> 4) & 1, t >> 5, sA, sB);
  }
}

// ===========================================================================
// Launch
// ===========================================================================
extern "C" void kernel_launch(void* const* d_in, const int* in_sizes, int n_in,
                              void* d_out, int out_size, void* d_ws,
                              size_t ws_size, hipStream_t stream) {
  const float* l1 = (const float*)d_in[0];
  const float* xyz1 = (const float*)d_in[1];
  const float* l2 = (const float*)d_in[2];
  const float* xyz2 = (const float*)d_in[3];
  const float* q1w = (const float*)d_in[4];
  const float* k1w = (const float*)d_in[5];
  const float* mlp_w1 = (const float*)d_in[6];
  const float* mlp_b1 = (const float*)d_in[7];
  const float* mlp_g1 = (const float*)d_in[8];
  const float* mlp_be1 = (const float*)d_in[9];
  const float* mlp_w2 = (const float*)d_in[10];
  const float* mlp_b2 = (const float*)d_in[11];
  const float* qw = (const float*)d_in[12];
  const float* kw = (const float*)d_in[13];
  const float* vw = (const float*)d_in[14];
  const float* posw = (const float*)d_in[15];
  const float* norm_g = (const float*)d_in[16];
  const float* norm_b = (const float*)d_in[17];
  const float* m1_w1 = (const float*)d_in[18];
  const float* m1_b1 = (const float*)d_in[19];
  const float* m1_g = (const float*)d_in[20];
  const float* m1_be = (const float*)d_in[21];
  const float* m1_w2 = (const float*)d_in[22];
  const float* m1_b2 = (const float*)d_in[23];

  char* ws = (char*)d_ws;
  unsigned short* wb_mlp_w1 = (unsigned short*)(ws + 0);
  unsigned short* wb_mlp_w2 = (unsigned short*)(ws + 131072);
  unsigned short* wb_qw = (unsigned short*)(ws + 393216);
  unsigned short* wb_kw = (unsigned short*)(ws + 917504);
  unsigned short* wb_vw = (unsigned short*)(ws + 1441792);
  unsigned short* wb_m1w1 = (unsigned short*)(ws + 1966080);
  unsigned short* wb_m1w2 = (unsigned short*)(ws + 2490368);
  float* scores = (float*)(ws + 2752512);
  int* idxb = (int*)(ws + 2891776);
  float* p1selT = (float*)(ws + 2924544);
  float* q1v = (float*)(ws + 3022848);
  float* wvec = (float*)(ws + 3399680);
  const long MiB = 1048576;
  unsigned short* l1selT = (unsigned short*)(ws + 4 * MiB);
  unsigned short* qinT = (unsigned short*)(ws + 20 * MiB);
  float* l2T = (float*)(ws + 36 * MiB);

  // zero: wvec + stats + barrier counter  [3399680, 3399680+241664)
  hipMemsetAsync(ws + 3399680, 0, 241664, stream);

  prep_kernel<<<dim3(1024, 9), 256, 0, stream>>>(
      mlp_w1, mlp_w2, qw, kw, vw, m1_w1, m1_w2,
      wb_mlp_w1, wb_mlp_w2, wb_qw, wb_kw, wb_vw, wb_m1w1, wb_m1w2,
      l1, q1w, q1v, l2, xyz2, posw, qinT, l2T);
  selB_kernel<<<dim3(8, 8), 256, 0, stream>>>(k1w, q1v, wvec);
  sel_scores_kernel<<<dim3(16, 8), 256, 0, stream>>>(l1, wvec, scores);
  topk_select_kernel<<<8, 256, 0, stream>>>(scores, idxb);
  gather_sel_kernel<<<dim3(16, 2, 8), 256, 0, stream>>>(l1, xyz1, idxb, l1selT, p1selT);

  mega_kernel<<<512, 256, 0, stream>>>(
      ws, (float*)d_out, mlp_b1, mlp_g1, mlp_be1, mlp_b2, posw,
      norm_g, norm_b, m1_b1, m1_g, m1_be, m1_b2);
}